// Round 8
// baseline (255.346 us; speedup 1.0000x reference)
//
#include <hip/hip_runtime.h>

// ---------------- constants (match reference) ----------------
// B,H,W,F,D = 8,126,126,64,32 ; grid fields are (8,128,128,32)
#define NITER 20
#define OUTER 3

constexpr double DXd  = 2.0 / 9.0;     // 2/(B+1)
constexpr double DYd  = 2.0 / 127.0;   // 2/(H+1)
constexpr double DX2d = DXd * DXd;
constexpr double DY2d = DYd * DYd;
constexpr double DENd = 2.0 * (DX2d + DY2d);

constexpr float K1     = (float)(DY2d / DENd);          // * (E+W)
constexpr float K2     = (float)(DX2d / DENd);          // * (N+S)
constexpr float CC     = (float)(DX2d * DY2d / DENd);   // c coefficient
constexpr float INV2DX = (float)(1.0 / (2.0 * DXd));
constexpr float INV2DY = (float)(1.0 / (2.0 * DYd));
constexpr float INVDT  = (float)(1.0 / 0.1);
constexpr float DTDX   = (float)(0.1 / DXd);
constexpr float DTDY   = (float)(0.1 / DYd);
constexpr float PGX    = (float)(0.1 / (2.0 * 1.0 * DXd)); // DT/(2 RHO DX)
constexpr float PGY    = (float)(0.1 / (2.0 * 1.0 * DYd));
constexpr float A1     = (float)(0.1 / DX2d);            // DT/DX2
constexpr float A2     = (float)(0.1 / DY2d);            // DT/DY2
constexpr float NUf    = 0.1f;
constexpr float FDT    = 0.1f;                           // FRC*DT

// DPP 16-lane-row rotates (VALU pipe; E/W halo with free periodic-128 wrap).
// Verified correct in Rounds 6-7. Runtime probe resolves direction convention.
#define ROR1(x)  __int_as_float(__builtin_amdgcn_mov_dpp(__float_as_int(x), 0x121, 0xF, 0xF, false))
#define ROR15(x) __int_as_float(__builtin_amdgcn_mov_dpp(__float_as_int(x), 0x12F, 0xF, 0xF, false))
#define FROM_LO(x) (selLower ? ROR1(x) : ROR15(x))   // value from tx-1 (periodic in 16)
#define FROM_HI(x) (selLower ? ROR15(x) : ROR1(x))   // value from tx+1 (periodic in 16)

// Split-half LDS row layout (R7-verified, 0 bank conflicts): row of 128 cols is
// stored {c0..c3 of tx0..15}{c4..c7 of tx0..15} -> all float4 accesses are
// 16B-stride contiguous across the 16 tx -> uniform bank load. Legal because
// each address is only ever touched by the same tx (E/W halos come from DPP).
#define PLOAD(dst, arr, row) do { \
    float4 _a = *(const float4*)&(arr)[(row) * 128 + (tx << 2)]; \
    float4 _b = *(const float4*)&(arr)[(row) * 128 + 64 + (tx << 2)]; \
    (dst)[0]=_a.x; (dst)[1]=_a.y; (dst)[2]=_a.z; (dst)[3]=_a.w; \
    (dst)[4]=_b.x; (dst)[5]=_b.y; (dst)[6]=_b.z; (dst)[7]=_b.w; } while (0)
#define PSTORE(arr, row, src) do { \
    *(float4*)&(arr)[(row) * 128 + (tx << 2)] = make_float4((src)[0],(src)[1],(src)[2],(src)[3]); \
    *(float4*)&(arr)[(row) * 128 + 64 + (tx << 2)] = make_float4((src)[4],(src)[5],(src)[6],(src)[7]); } while (0)

// One Jacobi iteration, register ping-pong SRC -> DST (no snapshots: SRC is
// never modified, so all neighbor reads are OLD by construction).
#define JSTEP(SRC, DST) do { \
    float nrow[8], shalo[8]; \
    PLOAD(nrow,  sP, s * 64 + tyN * 2 + 1);   /* old row r0-1 */ \
    PLOAD(shalo, sP, s * 64 + tyS * 2 + 0);   /* old row r0+4 */ \
    _Pragma("unroll") \
    for (int r = 0; r < 4; ++r) { \
        float pWh = FROM_LO(SRC[r][7]); \
        float pEh = FROM_HI(SRC[r][0]); \
        _Pragma("unroll") \
        for (int c = 0; c < 8; ++c) { \
            float E = (c < 7) ? SRC[r][c + 1] : pEh; \
            float W = (c > 0) ? SRC[r][c - 1] : pWh; \
            float N = (r > 0) ? SRC[r - 1][c] : nrow[c]; \
            float S = (r < 3) ? SRC[r + 1][c] : shalo[c]; \
            DST[r][c] = (E + W) * K1 + (N + S) * K2 - cb[r][c]; \
        } \
    } \
    if (ty == 0)  { _Pragma("unroll") for (int c = 0; c < 8; ++c) DST[0][c] = DST[1][c]; } \
    if (ty == 31) { _Pragma("unroll") for (int c = 0; c < 8; ++c) DST[3][c] = DST[2][c]; } \
    PSTORE(sP, (s ^ 1) * 64 + ty * 2 + 0, DST[0]); \
    PSTORE(sP, (s ^ 1) * 64 + ty * 2 + 1, DST[3]); \
    __syncthreads(); \
    s ^= 1; \
} while (0)

// ---------------- kernel 1: p0 = einsum(pad(x), w) + b_lin, planar [b][d][128][128]
__global__ __launch_bounds__(256) void einsum_kernel(
    const float* __restrict__ x, const float* __restrict__ w,
    const float* __restrict__ bl, float* __restrict__ p0)
{
    int id = blockIdx.x * 256 + threadIdx.x;
    int c = id & 127, r = (id >> 7) & 127, b = id >> 14;
    float acc[32];
#pragma unroll
    for (int d = 0; d < 32; ++d) acc[d] = bl[d];
    if (r >= 1 && r <= 126 && c >= 1 && c <= 126) {
        const float* xp = x + (((size_t)(b * 126 + (r - 1))) * 126 + (c - 1)) * 64;
#pragma unroll
        for (int f = 0; f < 64; f += 4) {
            float4 xv = *(const float4*)(xp + f);
#pragma unroll
            for (int d = 0; d < 32; ++d) {
                acc[d] += xv.x * w[d * 64 + f] + xv.y * w[d * 64 + f + 1]
                        + xv.z * w[d * 64 + f + 2] + xv.w * w[d * 64 + f + 3];
            }
        }
    }
    float* op = p0 + ((size_t)b * 32) * 16384 + r * 128 + c;
#pragma unroll
    for (int d = 0; d < 32; ++d) op[(size_t)d * 16384] = acc[d];
}

// ---------------- kernel 2: the full 3-outer-iteration simulation ----------------
// one workgroup per (b,d) plane; 512 threads = 16 tx (8 cols, DPP ring) x 32 ty (4 rows).
//
// Round-8 consolidation. Empirical launch-bounds model: 2nd arg acts as
// min-BLOCKS/CU -> (512,2) capped VGPR at 128 (R6's all-register design spilled
// under it). (512,1) -> 256-VGPR cap; 1 block/CU is structurally true anyway
// (grid == #CUs). This admits the best-of-all-rounds combination:
//  - u,v,cb in REGISTERS (no plane loads; R7's plane streaming paid 2 extra
//    LDS exposures + movs per phase for nothing once spill is gone)
//  - DPP E/W exchange (R6/R7), split-half seam layout (R7, 0 conflicts)
//  - p seams ping-pong in LDS -> 1 barrier + 1 LDS exposure per Jacobi iter
//  - Jacobi unrolled x2 as pA->pB / pB->pA: zero snapshot/copy movs
// LDS = 64K (sP ping-pong) + 32K (sUs) + 32K (sVs) = 128 KiB.
__global__ __launch_bounds__(512, 1) void sim_kernel(
    const float* __restrict__ u0, const float* __restrict__ v0,
    const float* __restrict__ p0ws, const float* __restrict__ x,
    const float* __restrict__ w, const float* __restrict__ bl,
    float* __restrict__ out, int use_ws)
{
    __shared__ float sP[2 * 32 * 2 * 128];   // 64 KiB: p seam rows {0,3}/ty, ping-pong
    __shared__ float sUs[32 * 2 * 128];      // 32 KiB: u seam rows {0,3}/ty
    __shared__ float sVs[32 * 2 * 128];      // 32 KiB: v seam rows {0,3}/ty

    const int tid = threadIdx.x;
    const int tx = tid & 15, ty = tid >> 4;
    const int c0 = tx << 3, r0 = ty << 2;
    const int lane = tid & 63;
    const int bb = blockIdx.x & 7;   // batch
    const int d  = blockIdx.x >> 3;  // channel
    const int tyN = (ty > 0) ? ty - 1 : 0;     // clamped: garbage masked by BC overwrite
    const int tyS = (ty < 31) ? ty + 1 : 31;

    // runtime DPP-direction probe: does ROW_ROR:1 source from lane-1 (mod 16)?
    const int pr = __builtin_amdgcn_mov_dpp(lane, 0x121, 0xF, 0xF, false);
    const bool selLower = (pr == ((lane & 48) | ((lane + 15) & 15)));

    float pA[4][8], pB[4][8], uC[4][8], vC[4][8], cb[4][8];

    // ---- load u, v (strided channel reads, one-time) ----
#pragma unroll
    for (int r = 0; r < 4; ++r) {
        const size_t base = ((size_t)((bb * 128 + (r0 + r)) * 128 + c0)) * 32 + d;
#pragma unroll
        for (int c = 0; c < 8; ++c) {
            uC[r][c] = u0[base + (size_t)c * 32];
            vC[r][c] = v0[base + (size_t)c * 32];
        }
    }

    // ---- initial p -> pA ----
    if (use_ws) {
        const float* pp = p0ws + ((size_t)(bb * 32 + d)) * 16384;
#pragma unroll
        for (int r = 0; r < 4; ++r) {
            float4 a = *(const float4*)(pp + (r0 + r) * 128 + c0);
            float4 b = *(const float4*)(pp + (r0 + r) * 128 + c0 + 4);
            pA[r][0] = a.x; pA[r][1] = a.y; pA[r][2] = a.z; pA[r][3] = a.w;
            pA[r][4] = b.x; pA[r][5] = b.y; pA[r][6] = b.z; pA[r][7] = b.w;
        }
    } else {
        const float blv = bl[d];
#pragma unroll
        for (int r = 0; r < 4; ++r) {
            const int gr = r0 + r;
#pragma unroll
            for (int c = 0; c < 8; ++c) {
                const int gc = c0 + c;
                float acc = blv;
                if (gr >= 1 && gr <= 126 && gc >= 1 && gc <= 126) {
                    const float* xp = x + (((size_t)(bb * 126 + (gr - 1))) * 126 + (gc - 1)) * 64;
                    for (int f = 0; f < 64; f += 4) {
                        float4 xv = *(const float4*)(xp + f);
                        acc += xv.x * w[d * 64 + f] + xv.y * w[d * 64 + f + 1]
                             + xv.z * w[d * 64 + f + 2] + xv.w * w[d * 64 + f + 3];
                    }
                }
                pA[r][c] = acc;
            }
        }
    }

    // ---- initial seam publish: p -> sP buf0, u,v -> sUs/sVs ----
    PSTORE(sP,  ty * 2 + 0, pA[0]);
    PSTORE(sP,  ty * 2 + 1, pA[3]);
    PSTORE(sUs, ty * 2 + 0, uC[0]);
    PSTORE(sUs, ty * 2 + 1, uC[3]);
    PSTORE(sVs, ty * 2 + 0, vC[0]);
    PSTORE(sVs, ty * 2 + 1, vC[3]);
    __syncthreads();
    int s = 0;

    for (int outer = 0; outer < OUTER; ++outer) {
        // ================= build_b -> cb = CC * b =================
        {
            float uNh[8], uSh[8], vNh[8], vSh[8];
            PLOAD(uNh, sUs, tyN * 2 + 1);   // u row r0-1
            PLOAD(uSh, sUs, tyS * 2 + 0);   // u row r0+4
            PLOAD(vNh, sVs, tyN * 2 + 1);
            PLOAD(vSh, sVs, tyS * 2 + 0);
#pragma unroll
            for (int r = 0; r < 4; ++r) {
                float uWh = FROM_LO(uC[r][7]);
                float uEh = FROM_HI(uC[r][0]);
                float vWh = FROM_LO(vC[r][7]);
                float vEh = FROM_HI(vC[r][0]);
#pragma unroll
                for (int c = 0; c < 8; ++c) {
                    float uE = (c < 7) ? uC[r][c + 1] : uEh;
                    float uW = (c > 0) ? uC[r][c - 1] : uWh;
                    float vE = (c < 7) ? vC[r][c + 1] : vEh;
                    float vW = (c > 0) ? vC[r][c - 1] : vWh;
                    float uN = (r > 0) ? uC[r - 1][c] : uNh[c];
                    float uS = (r < 3) ? uC[r + 1][c] : uSh[c];
                    float vN = (r > 0) ? vC[r - 1][c] : vNh[c];
                    float vS = (r < 3) ? vC[r + 1][c] : vSh[c];
                    float dudx = (uE - uW) * INV2DX;
                    float dvdy = (vS - vN) * INV2DY;
                    float dudy = (uS - uN) * INV2DY;
                    float dvdx = (vE - vW) * INV2DX;
                    float bt = (dudx + dvdy) * INVDT - dudx * dudx
                             - 2.0f * dudy * dvdx - dvdy * dvdy;   // RHO == 1
                    cb[r][c] = CC * bt;   // garbage at rows 0/127: masked by p BCs
                }
            }
        }
        // sUs/sVs not rewritten until velocity; sP untouched -> no barrier needed.

        // ================= pressure_poisson: 20 Jacobi iterations (2x unrolled) ======
        for (int it2 = 0; it2 < NITER / 2; ++it2) {
            JSTEP(pA, pB);
            JSTEP(pB, pA);
        }
        // NITER even -> final p in pA; final seams in sP buf s.

        // ================= velocity_step (skipped after last outer: output is p) ========
        if (outer < OUTER - 1) {
            float uNh[8], uSh[8], vNh[8], vSh[8], pNh[8], pSh[8];
            PLOAD(uNh, sUs, tyN * 2 + 1);
            PLOAD(uSh, sUs, tyS * 2 + 0);
            PLOAD(vNh, sVs, tyN * 2 + 1);
            PLOAD(vSh, sVs, tyS * 2 + 0);
            PLOAD(pNh, sP, s * 64 + tyN * 2 + 1);   // final p row r0-1
            PLOAD(pSh, sP, s * 64 + tyS * 2 + 0);   // final p row r0+4
            __syncthreads();   // all halo reads done before sUs/sVs rewrites below

            float uNrow[8], vNrow[8];
#pragma unroll
            for (int c = 0; c < 8; ++c) { uNrow[c] = uNh[c]; vNrow[c] = vNh[c]; }
#pragma unroll
            for (int r = 0; r < 4; ++r) {
                float uold[8], vold[8];  // snapshot: same-row + prior-row reads must be OLD
#pragma unroll
                for (int c = 0; c < 8; ++c) { uold[c] = uC[r][c]; vold[c] = vC[r][c]; }
                float uWh = FROM_LO(uold[7]);
                float uEh = FROM_HI(uold[0]);
                float vWh = FROM_LO(vold[7]);
                float vEh = FROM_HI(vold[0]);
                float pWh = FROM_LO(pA[r][7]);
                float pEh = FROM_HI(pA[r][0]);
#pragma unroll
                for (int c = 0; c < 8; ++c) {
                    float uc = uold[c], vc = vold[c];
                    float uE = (c < 7) ? uold[c + 1] : uEh;
                    float uW = (c > 0) ? uold[c - 1] : uWh;
                    float vE = (c < 7) ? vold[c + 1] : vEh;
                    float vW = (c > 0) ? vold[c - 1] : vWh;
                    float uN = uNrow[c];
                    float uS = (r < 3) ? uC[r + 1][c] : uSh[c];
                    float vN = vNrow[c];
                    float vS = (r < 3) ? vC[r + 1][c] : vSh[c];
                    float pE = (c < 7) ? pA[r][c + 1] : pEh;
                    float pW = (c > 0) ? pA[r][c - 1] : pWh;
                    float pN = (r > 0) ? pA[r - 1][c] : pNh[c];
                    float pS = (r < 3) ? pA[r + 1][c] : pSh[c];

                    float unew = uc - uc * DTDX * (uc - uW) - vc * DTDY * (uc - uN)
                               - PGX * (pE - pW)
                               + NUf * (A1 * (uE - 2.0f * uc + uW) + A2 * (uS - 2.0f * uc + uN))
                               + FDT;
                    float vnew = vc - uc * DTDX * (vc - vW) - vc * DTDY * (vc - vN)
                               - PGY * (pS - pN)
                               + NUf * (A1 * (vE - 2.0f * vc + vW) + A2 * (vS - 2.0f * vc + vN));
                    uC[r][c] = unew;
                    vC[r][c] = vnew;
                }
#pragma unroll
                for (int c = 0; c < 8; ++c) { uNrow[c] = uold[c]; vNrow[c] = vold[c]; }
            }
            // u,v row BCs: global rows 0 and 127 -> 0 (masks clamped-halo garbage)
            if (ty == 0) {
#pragma unroll
                for (int c = 0; c < 8; ++c) { uC[0][c] = 0.0f; vC[0][c] = 0.0f; }
            }
            if (ty == 31) {
#pragma unroll
                for (int c = 0; c < 8; ++c) { uC[3][c] = 0.0f; vC[3][c] = 0.0f; }
            }
            // publish NEW u,v seams for next outer's build_b
            PSTORE(sUs, ty * 2 + 0, uC[0]);
            PSTORE(sUs, ty * 2 + 1, uC[3]);
            PSTORE(sVs, ty * 2 + 0, vC[0]);
            PSTORE(sVs, ty * 2 + 1, vC[3]);
            __syncthreads();
        }
    }

    // ---- output: p[:, row 127, :, :]  -> out[b][col][d] ----
    if (ty == 31) {
        float* op = out + ((size_t)bb * 128 + c0) * 32 + d;
#pragma unroll
        for (int c = 0; c < 8; ++c) op[(size_t)c * 32] = pA[3][c];
    }
}

extern "C" void kernel_launch(void* const* d_in, const int* in_sizes, int n_in,
                              void* d_out, int out_size, void* d_ws, size_t ws_size,
                              hipStream_t stream) {
    const float* x  = (const float*)d_in[0];
    const float* u0 = (const float*)d_in[1];
    const float* v0 = (const float*)d_in[2];
    const float* w  = (const float*)d_in[3];
    const float* bl = (const float*)d_in[4];
    float* out = (float*)d_out;
    float* p0  = (float*)d_ws;

    const size_t need = (size_t)8 * 32 * 128 * 128 * sizeof(float);
    const int use_ws = (ws_size >= need) ? 1 : 0;

    if (use_ws) {
        einsum_kernel<<<512, 256, 0, stream>>>(x, w, bl, p0);
    }
    sim_kernel<<<256, 512, 0, stream>>>(u0, v0, p0, x, w, bl, out, use_ws);
}

// Round 9
// 237.653 us; speedup vs baseline: 1.0744x; 1.0744x over previous
//
#include <hip/hip_runtime.h>

// ---------------- constants (match reference) ----------------
// B,H,W,F,D = 8,126,126,64,32 ; grid fields are (8,128,128,32)
#define NITER 20
#define OUTER 3

constexpr double DXd  = 2.0 / 9.0;     // 2/(B+1)
constexpr double DYd  = 2.0 / 127.0;   // 2/(H+1)
constexpr double DX2d = DXd * DXd;
constexpr double DY2d = DYd * DYd;
constexpr double DENd = 2.0 * (DX2d + DY2d);

constexpr float K1     = (float)(DY2d / DENd);          // * (E+W)
constexpr float K2     = (float)(DX2d / DENd);          // * (N+S)
constexpr float CC     = (float)(DX2d * DY2d / DENd);   // c coefficient
constexpr float NCC    = -CC;                            // cb stored NEGATED -> pure-FMA Jacobi
constexpr float INV2DX = (float)(1.0 / (2.0 * DXd));
constexpr float INV2DY = (float)(1.0 / (2.0 * DYd));
constexpr float INVDT  = (float)(1.0 / 0.1);
constexpr float DTDX   = (float)(0.1 / DXd);
constexpr float DTDY   = (float)(0.1 / DYd);
constexpr float PGX    = (float)(0.1 / (2.0 * 1.0 * DXd)); // DT/(2 RHO DX)
constexpr float PGY    = (float)(0.1 / (2.0 * 1.0 * DYd));
constexpr float A1     = (float)(0.1 / DX2d);            // DT/DX2
constexpr float A2     = (float)(0.1 / DY2d);            // DT/DY2
constexpr float NUf    = 0.1f;
constexpr float FDT    = 0.1f;                           // FRC*DT

// DPP 16-lane-row rotates (VALU pipe; E/W halo with free periodic-128 wrap).
// Verified correct in Rounds 6-8. Runtime probe resolves direction convention.
#define ROR1(x)  __int_as_float(__builtin_amdgcn_mov_dpp(__float_as_int(x), 0x121, 0xF, 0xF, false))
#define ROR15(x) __int_as_float(__builtin_amdgcn_mov_dpp(__float_as_int(x), 0x12F, 0xF, 0xF, false))
#define FROM_LO(x) (selLower ? ROR1(x) : ROR15(x))   // value from tx-1 (periodic in 16)
#define FROM_HI(x) (selLower ? ROR15(x) : ROR1(x))   // value from tx+1 (periodic in 16)

// Split-half LDS row layout (R7-verified, 0 bank conflicts): row of 128 cols is
// stored {c0..c3 of tx0..15}{c4..c7 of tx0..15} -> all float4 accesses are
// 16B-stride contiguous across the 16 tx -> uniform bank load. Legal because
// each address is only ever touched by the same tx (E/W halos come from DPP).
#define PLOAD(dst, arr, row) do { \
    float4 _a = *(const float4*)&(arr)[(row) * 128 + (tx << 2)]; \
    float4 _b = *(const float4*)&(arr)[(row) * 128 + 64 + (tx << 2)]; \
    (dst)[0]=_a.x; (dst)[1]=_a.y; (dst)[2]=_a.z; (dst)[3]=_a.w; \
    (dst)[4]=_b.x; (dst)[5]=_b.y; (dst)[6]=_b.z; (dst)[7]=_b.w; } while (0)
#define PSTORE(arr, row, src) do { \
    *(float4*)&(arr)[(row) * 128 + (tx << 2)] = make_float4((src)[0],(src)[1],(src)[2],(src)[3]); \
    *(float4*)&(arr)[(row) * 128 + 64 + (tx << 2)] = make_float4((src)[4],(src)[5],(src)[6],(src)[7]); } while (0)

// One Jacobi iteration, register ping-pong SRC -> DST (no snapshot movs: SRC is
// never modified, so all neighbor reads are OLD by construction). Single-buffer
// seams (sPm) with 2 barriers — R4 vs R7 showed barrier count is not binding.
// Pure-FMA cell update: cb holds -CC*b, so cell = fma(E+W,K1, fma(N+S,K2,cb)).
#define JSTEP(SRC, DST) do { \
    float nrow[8], shalo[8]; \
    PLOAD(nrow,  sPm, tyN * 2 + 1);   /* old row r0-1 */ \
    PLOAD(shalo, sPm, tyS * 2 + 0);   /* old row r0+4 */ \
    _Pragma("unroll") \
    for (int r = 0; r < 4; ++r) { \
        float pWh = FROM_LO(SRC[r][7]); \
        float pEh = FROM_HI(SRC[r][0]); \
        _Pragma("unroll") \
        for (int c = 0; c < 8; ++c) { \
            float E = (c < 7) ? SRC[r][c + 1] : pEh; \
            float W = (c > 0) ? SRC[r][c - 1] : pWh; \
            float N = (r > 0) ? SRC[r - 1][c] : nrow[c]; \
            float S = (r < 3) ? SRC[r + 1][c] : shalo[c]; \
            DST[r][c] = fmaf(E + W, K1, fmaf(N + S, K2, cb[r][c])); \
        } \
    } \
    if (ty == 0)  { _Pragma("unroll") for (int c = 0; c < 8; ++c) DST[0][c] = DST[1][c]; } \
    if (ty == 31) { _Pragma("unroll") for (int c = 0; c < 8; ++c) DST[3][c] = DST[2][c]; } \
    __syncthreads();        /* all reads of old seams done before rewrite */ \
    PSTORE(sPm, ty * 2 + 0, DST[0]); \
    PSTORE(sPm, ty * 2 + 1, DST[3]); \
    __syncthreads();        /* new seams visible */ \
} while (0)

// ---------------- kernel 1: p0 = einsum(pad(x), w) + b_lin, planar [b][d][128][128]
__global__ __launch_bounds__(256) void einsum_kernel(
    const float* __restrict__ x, const float* __restrict__ w,
    const float* __restrict__ bl, float* __restrict__ p0)
{
    int id = blockIdx.x * 256 + threadIdx.x;
    int c = id & 127, r = (id >> 7) & 127, b = id >> 14;
    float acc[32];
#pragma unroll
    for (int d = 0; d < 32; ++d) acc[d] = bl[d];
    if (r >= 1 && r <= 126 && c >= 1 && c <= 126) {
        const float* xp = x + (((size_t)(b * 126 + (r - 1))) * 126 + (c - 1)) * 64;
#pragma unroll
        for (int f = 0; f < 64; f += 4) {
            float4 xv = *(const float4*)(xp + f);
#pragma unroll
            for (int d = 0; d < 32; ++d) {
                acc[d] += xv.x * w[d * 64 + f] + xv.y * w[d * 64 + f + 1]
                        + xv.z * w[d * 64 + f + 2] + xv.w * w[d * 64 + f + 3];
            }
        }
    }
    float* op = p0 + ((size_t)b * 32) * 16384 + r * 128 + c;
#pragma unroll
    for (int d = 0; d < 32; ++d) op[(size_t)d * 16384] = acc[d];
}

// ---------------- kernel 2: the full 3-outer-iteration simulation ----------------
// one workgroup per (b,d) plane; 512 threads = 16 tx (8 cols, DPP ring) x 32 ty (4 rows).
//
// Round-9 = R7 structure (u,v as LDS planes -> Jacobi registers lean; proved
// 104 VGPR / zero spill / zero conflicts / 128 us) + R8's register-ping-pong
// Jacobi (kills the 64 snapshot movs/iter; R8 spilled only because uC,vC also
// lived in registers — here they don't) + pure-FMA cell update (cb pre-negated,
// 4 ops/cell vs 5). Jacobi VALU count drops ~30% in the phase that is 55% of
// all issued instructions. Register budget: pA(32)+pB(32)+cb(32)+halos(16)
// +temps ~ 120 < 128 cap.
// LDS = 64K (sU plane) + 64K (sV plane) + 32K (sPm p-seams) = 160 KiB.
__global__ __launch_bounds__(512, 2) void sim_kernel(
    const float* __restrict__ u0, const float* __restrict__ v0,
    const float* __restrict__ p0ws, const float* __restrict__ x,
    const float* __restrict__ w, const float* __restrict__ bl,
    float* __restrict__ out, int use_ws)
{
    __shared__ float sU[128 * 128];     // 64 KiB  u plane (split-half rows)
    __shared__ float sV[128 * 128];     // 64 KiB  v plane
    __shared__ float sPm[32 * 2 * 128]; // 32 KiB  p seam rows {0,3} per ty

    const int tid = threadIdx.x;
    const int tx = tid & 15, ty = tid >> 4;
    const int c0 = tx << 3, r0 = ty << 2;
    const int lane = tid & 63;
    const int bb = blockIdx.x & 7;   // batch
    const int d  = blockIdx.x >> 3;  // channel
    const int tyN = (ty > 0) ? ty - 1 : 0;     // clamped: garbage masked by BC overwrite
    const int tyS = (ty < 31) ? ty + 1 : 31;
    const int rowN = (r0 > 0) ? r0 - 1 : 0;        // clamped plane halo rows
    const int rowS = (r0 + 4 < 128) ? r0 + 4 : 127;

    // runtime DPP-direction probe: does ROW_ROR:1 source from lane-1 (mod 16)?
    const int pr = __builtin_amdgcn_mov_dpp(lane, 0x121, 0xF, 0xF, false);
    const bool selLower = (pr == ((lane & 48) | ((lane + 15) & 15)));

    float pA[4][8], pB[4][8];

    // ---- load u, v from global (one-time) straight into LDS planes ----
#pragma unroll
    for (int r = 0; r < 4; ++r) {
        const size_t base = ((size_t)((bb * 128 + (r0 + r)) * 128 + c0)) * 32 + d;
        float ut[8], vt[8];
#pragma unroll
        for (int c = 0; c < 8; ++c) {
            ut[c] = u0[base + (size_t)c * 32];
            vt[c] = v0[base + (size_t)c * 32];
        }
        PSTORE(sU, r0 + r, ut);
        PSTORE(sV, r0 + r, vt);
    }

    // ---- initial p -> pA ----
    if (use_ws) {
        const float* pp = p0ws + ((size_t)(bb * 32 + d)) * 16384;
#pragma unroll
        for (int r = 0; r < 4; ++r) {
            float4 a = *(const float4*)(pp + (r0 + r) * 128 + c0);
            float4 b = *(const float4*)(pp + (r0 + r) * 128 + c0 + 4);
            pA[r][0] = a.x; pA[r][1] = a.y; pA[r][2] = a.z; pA[r][3] = a.w;
            pA[r][4] = b.x; pA[r][5] = b.y; pA[r][6] = b.z; pA[r][7] = b.w;
        }
    } else {
        const float blv = bl[d];
#pragma unroll
        for (int r = 0; r < 4; ++r) {
            const int gr = r0 + r;
#pragma unroll
            for (int c = 0; c < 8; ++c) {
                const int gc = c0 + c;
                float acc = blv;
                if (gr >= 1 && gr <= 126 && gc >= 1 && gc <= 126) {
                    const float* xp = x + (((size_t)(bb * 126 + (gr - 1))) * 126 + (gc - 1)) * 64;
                    for (int f = 0; f < 64; f += 4) {
                        float4 xv = *(const float4*)(xp + f);
                        acc += xv.x * w[d * 64 + f] + xv.y * w[d * 64 + f + 1]
                             + xv.z * w[d * 64 + f + 2] + xv.w * w[d * 64 + f + 3];
                    }
                }
                pA[r][c] = acc;
            }
        }
    }

    // ---- initial p seam publish ----
    PSTORE(sPm, ty * 2 + 0, pA[0]);
    PSTORE(sPm, ty * 2 + 1, pA[3]);
    __syncthreads();

    for (int outer = 0; outer < OUTER; ++outer) {
        // ================= build_b -> cb = (-CC) * b (streamed from LDS planes) ======
        float cb[4][8];
        {
            float um[8], uc[8], up[8], vm[8], vc[8], vp[8];
            PLOAD(um, sU, rowN); PLOAD(vm, sV, rowN);
            PLOAD(uc, sU, r0);   PLOAD(vc, sV, r0);
#pragma unroll
            for (int r = 0; r < 4; ++r) {
                const int rn = (r < 3) ? (r0 + r + 1) : rowS;
                PLOAD(up, sU, rn); PLOAD(vp, sV, rn);
                float uWh = FROM_LO(uc[7]);
                float uEh = FROM_HI(uc[0]);
                float vWh = FROM_LO(vc[7]);
                float vEh = FROM_HI(vc[0]);
#pragma unroll
                for (int c = 0; c < 8; ++c) {
                    float uE = (c < 7) ? uc[c + 1] : uEh;
                    float uW = (c > 0) ? uc[c - 1] : uWh;
                    float vE = (c < 7) ? vc[c + 1] : vEh;
                    float vW = (c > 0) ? vc[c - 1] : vWh;
                    float dudx = (uE - uW) * INV2DX;
                    float dvdy = (vp[c] - vm[c]) * INV2DY;
                    float dudy = (up[c] - um[c]) * INV2DY;
                    float dvdx = (vE - vW) * INV2DX;
                    float bt = (dudx + dvdy) * INVDT - dudx * dudx
                             - 2.0f * dudy * dvdx - dvdy * dvdy;   // RHO == 1
                    cb[r][c] = NCC * bt;   // NEGATED; garbage at rows 0/127 masked by p BCs
                }
#pragma unroll
                for (int c = 0; c < 8; ++c) {
                    um[c] = uc[c]; uc[c] = up[c];
                    vm[c] = vc[c]; vc[c] = vp[c];
                }
            }
        }
        // planes stable through Jacobi (only sPm written); no barrier needed here.

        // ================= pressure_poisson: 20 Jacobi iterations (2x unrolled) ======
        for (int it2 = 0; it2 < NITER / 2; ++it2) {
            JSTEP(pA, pB);
            JSTEP(pB, pA);
        }
        // NITER even -> final p in pA; final seams in sPm.

        // ================= velocity_step (skipped after last outer: output is p) ========
        if (outer < OUTER - 1) {
            // Pre-read ALL cross-thread plane rows (rowN, rowS) before any plane write.
            float uSh[8], vSh[8], um[8], uc[8], up[8], vm[8], vc[8], vp[8];
            PLOAD(uSh, sU, rowS); PLOAD(vSh, sV, rowS);
            PLOAD(um, sU, rowN);  PLOAD(vm, sV, rowN);
            PLOAD(uc, sU, r0);    PLOAD(vc, sV, r0);      // own rows
            PLOAD(up, sU, r0 + 1); PLOAD(vp, sV, r0 + 1); // own rows
            __syncthreads();   // halo reads complete; own-row writes below are private
            float pNh[8], pSh[8];
            PLOAD(pNh, sPm, tyN * 2 + 1);   // final p row r0-1 (sPm stable during velocity)
            PLOAD(pSh, sPm, tyS * 2 + 0);   // final p row r0+4
#pragma unroll
            for (int r = 0; r < 4; ++r) {
                float uWh = FROM_LO(uc[7]);
                float uEh = FROM_HI(uc[0]);
                float vWh = FROM_LO(vc[7]);
                float vEh = FROM_HI(vc[0]);
                float pWh = FROM_LO(pA[r][7]);
                float pEh = FROM_HI(pA[r][0]);
                float un[8], vn[8];
#pragma unroll
                for (int c = 0; c < 8; ++c) {
                    float ucc = uc[c], vcc = vc[c];
                    float uE = (c < 7) ? uc[c + 1] : uEh;
                    float uW = (c > 0) ? uc[c - 1] : uWh;
                    float vE = (c < 7) ? vc[c + 1] : vEh;
                    float vW = (c > 0) ? vc[c - 1] : vWh;
                    float uN = um[c], uS = up[c];
                    float vN = vm[c], vS = vp[c];
                    float pE = (c < 7) ? pA[r][c + 1] : pEh;
                    float pW = (c > 0) ? pA[r][c - 1] : pWh;
                    float pN = (r > 0) ? pA[r - 1][c] : pNh[c];
                    float pS = (r < 3) ? pA[r + 1][c] : pSh[c];

                    un[c] = ucc - ucc * DTDX * (ucc - uW) - vcc * DTDY * (ucc - uN)
                          - PGX * (pE - pW)
                          + NUf * (A1 * (uE - 2.0f * ucc + uW) + A2 * (uS - 2.0f * ucc + uN))
                          + FDT;
                    vn[c] = vcc - ucc * DTDX * (vcc - vW) - vcc * DTDY * (vcc - vN)
                          - PGY * (pS - pN)
                          + NUf * (A1 * (vE - 2.0f * vcc + vW) + A2 * (vS - 2.0f * vcc + vN));
                }
                // u,v row BCs: global rows 0 and 127 -> 0 (masks clamped-halo garbage)
                if (ty == 0 && r == 0) {
#pragma unroll
                    for (int c = 0; c < 8; ++c) { un[c] = 0.0f; vn[c] = 0.0f; }
                }
                if (ty == 31 && r == 3) {
#pragma unroll
                    for (int c = 0; c < 8; ++c) { un[c] = 0.0f; vn[c] = 0.0f; }
                }
                PSTORE(sU, r0 + r, un);   // own row; neighbors pre-read their halos
                PSTORE(sV, r0 + r, vn);
                // rotate window (old values preserved in registers)
#pragma unroll
                for (int c = 0; c < 8; ++c) {
                    um[c] = uc[c]; uc[c] = up[c];
                    vm[c] = vc[c]; vc[c] = vp[c];
                }
                if (r < 2) {
                    PLOAD(up, sU, r0 + r + 2);   // own rows, not yet rewritten
                    PLOAD(vp, sV, r0 + r + 2);
                } else if (r == 2) {
#pragma unroll
                    for (int c = 0; c < 8; ++c) { up[c] = uSh[c]; vp[c] = vSh[c]; }
                }
            }
            __syncthreads();   // plane writes complete before next outer's build_b reads
        }
    }

    // ---- output: p[:, row 127, :, :]  -> out[b][col][d] ----
    if (ty == 31) {
        float* op = out + ((size_t)bb * 128 + c0) * 32 + d;
#pragma unroll
        for (int c = 0; c < 8; ++c) op[(size_t)c * 32] = pA[3][c];
    }
}

extern "C" void kernel_launch(void* const* d_in, const int* in_sizes, int n_in,
                              void* d_out, int out_size, void* d_ws, size_t ws_size,
                              hipStream_t stream) {
    const float* x  = (const float*)d_in[0];
    const float* u0 = (const float*)d_in[1];
    const float* v0 = (const float*)d_in[2];
    const float* w  = (const float*)d_in[3];
    const float* bl = (const float*)d_in[4];
    float* out = (float*)d_out;
    float* p0  = (float*)d_ws;

    const size_t need = (size_t)8 * 32 * 128 * 128 * sizeof(float);
    const int use_ws = (ws_size >= need) ? 1 : 0;

    if (use_ws) {
        einsum_kernel<<<512, 256, 0, stream>>>(x, w, bl, p0);
    }
    sim_kernel<<<256, 512, 0, stream>>>(u0, v0, p0, x, w, bl, out, use_ws);
}